// Round 14
// baseline (1030.329 us; speedup 1.0000x reference)
//
#include <hip/hip_runtime.h>
#include <math.h>

#define BB 2048
#define EMB 128
#define HID 512
#define G4 2048    // 4*HID
#define VT 8000
#define VTP2 8192  // padded vocab
#define NSTEP 9
#define NTILE2 64  // proj col tiles of 128
#define LDW 132    // epilogue transpose leading dim (floats)

typedef short bf16x8 __attribute__((ext_vector_type(8)));
typedef float f32x4 __attribute__((ext_vector_type(4)));

__device__ __forceinline__ ushort f2bf(float x) {
    uint u = __float_as_uint(x);
    uint r = (u + 0x7fffu + ((u >> 16) & 1u)) >> 16;
    return (ushort)r;
}
__device__ __forceinline__ float bf2f(ushort h) {
    return __uint_as_float(((uint)h) << 16);
}
__device__ __forceinline__ float sigm(float x) { return 1.0f / (1.0f + expf(-x)); }

// async global->LDS, 16B per lane, LDS dest = wave-uniform base + lane*16
__device__ __forceinline__ void gload16(const ushort* g, ushort* l) {
    __builtin_amdgcn_global_load_lds(
        (const __attribute__((address_space(1))) uint*)g,
        (__attribute__((address_space(3))) uint*)l, 16, 0, 0);
}

// ---- 64x128 tile staging: A 64x32 hi/lo + B 128x32 hi/lo (24 KB), 4 waves, 6 loads/thread ----
// ushort regions: A-hi [0,2048) A-lo [2048,4096) B-hi [4096,8192) B-lo [8192,12288)
__device__ __forceinline__ void stage6b(
    ushort* Sb,
    const ushort* __restrict__ Ah, const ushort* __restrict__ Al,
    const ushort* __restrict__ Bh, const ushort* __restrict__ Bl,
    int biA, int biB, int K, int k0, int wid, int lane)
{
    const int rl = lane >> 2, kcp = lane & 3;
    #pragma unroll
    for (int j = 0; j < 6; ++j) {
        int c = wid * 6 + j;               // 0..23, wave-uniform
        const ushort* src; int base, row;
        if (c < 4)       { src = Ah; base = biA; row = c * 16 + rl; }
        else if (c < 8)  { src = Al; base = biA; row = (c - 4) * 16 + rl; }
        else if (c < 16) { src = Bh; base = biB; row = (c - 8) * 16 + rl; }
        else             { src = Bl; base = biB; row = (c - 16) * 16 + rl; }
        int kc = (kcp - (row >> 1)) & 3;   // chunk rotation pre-swizzle
        gload16(src + (size_t)(base + row) * K + k0 + kc * 8, Sb + c * 512);
    }
}

// ---------------- fused gather: (finalize-argmax | src | BOS) -> embed -> hi/lo ----------------
__global__ __launch_bounds__(64) void gather2_kernel(
    ushort* __restrict__ Xhi, ushort* __restrict__ Xlo,
    const float* __restrict__ table,
    const int* __restrict__ src, int mode, int offset,
    const float* __restrict__ partval, const int* __restrict__ partidx)
{
    int row = blockIdx.x, t = threadIdx.x;
    int tok;
    if (mode == 0) {
        tok = src[row * 2 + offset];
    } else if (mode == 1) {
        tok = 0;
    } else {
        float v = partval[(size_t)row * NTILE2 + t];
        int  ix = partidx[(size_t)row * NTILE2 + t];
        #pragma unroll
        for (int off = 1; off < 64; off <<= 1) {
            float ov = __shfl_xor(v, off, 64);
            int   oi = __shfl_xor(ix, off, 64);
            if (ov > v || (ov == v && oi < ix)) { v = ov; ix = oi; }
        }
        tok = ix;
    }
    float2 e = *(const float2*)&table[(size_t)tok * EMB + t * 2];
    ushort2 hh, hl;
    hh.x = f2bf(e.x); hl.x = f2bf(e.x - bf2f(hh.x));
    hh.y = f2bf(e.y); hl.y = f2bf(e.y - bf2f(hh.y));
    *(ushort2*)&Xhi[row * EMB + t * 2] = hh;
    *(ushort2*)&Xlo[row * EMB + t * 2] = hl;
}

// ---------------- weight conversions ----------------
__global__ __launch_bounds__(256) void convgate_kernel(
    const float* __restrict__ W, ushort* __restrict__ Whi, ushort* __restrict__ Wlo,
    int kshift)
{
    size_t e0 = ((size_t)blockIdx.x * 256 + threadIdx.x) * 8;
    int K = 1 << kshift;
    int in_row = (int)(e0 >> kshift);
    int q = in_row & 511, gate = in_row >> 9;
    size_t o0 = (((size_t)(q * 4 + gate)) << kshift) + (e0 & (K - 1));
    float4 v0 = *(const float4*)&W[e0];
    float4 v1 = *(const float4*)&W[e0 + 4];
    float x[8] = {v0.x, v0.y, v0.z, v0.w, v1.x, v1.y, v1.z, v1.w};
    uint p[4], qq[4];
    #pragma unroll
    for (int j = 0; j < 4; ++j) {
        ushort h0 = f2bf(x[2 * j]),     l0 = f2bf(x[2 * j] - bf2f(h0));
        ushort h1 = f2bf(x[2 * j + 1]), l1 = f2bf(x[2 * j + 1] - bf2f(h1));
        p[j]  = (uint)h0 | ((uint)h1 << 16);
        qq[j] = (uint)l0 | ((uint)l1 << 16);
    }
    *(uint4*)&Whi[o0] = make_uint4(p[0], p[1], p[2], p[3]);
    *(uint4*)&Wlo[o0] = make_uint4(qq[0], qq[1], qq[2], qq[3]);
}

__global__ __launch_bounds__(256) void convgbias_kernel(
    const float* __restrict__ b0, const float* __restrict__ b1, float* __restrict__ bp)
{
    int i = blockIdx.x * 256 + threadIdx.x;   // G4 threads
    int q = i >> 2, gate = i & 3;
    bp[i] = b0[gate * 512 + q] + b1[gate * 512 + q];
}

__global__ __launch_bounds__(256) void convw_kernel(
    const float* __restrict__ W, ushort* __restrict__ Whi, ushort* __restrict__ Wlo)
{
    size_t e0 = ((size_t)blockIdx.x * 256 + threadIdx.x) * 8;  // VTP2*HID/8 threads
    int row = (int)(e0 >> 9);
    uint p[4], q[4];
    if (row < VT) {
        float4 v0 = *(const float4*)&W[e0];
        float4 v1 = *(const float4*)&W[e0 + 4];
        float x[8] = {v0.x, v0.y, v0.z, v0.w, v1.x, v1.y, v1.z, v1.w};
        #pragma unroll
        for (int j = 0; j < 4; ++j) {
            ushort h0 = f2bf(x[2 * j]),     l0 = f2bf(x[2 * j] - bf2f(h0));
            ushort h1 = f2bf(x[2 * j + 1]), l1 = f2bf(x[2 * j + 1] - bf2f(h1));
            p[j] = (uint)h0 | ((uint)h1 << 16);
            q[j] = (uint)l0 | ((uint)l1 << 16);
        }
    } else {
        #pragma unroll
        for (int j = 0; j < 4; ++j) { p[j] = 0u; q[j] = 0u; }
    }
    *(uint4*)&Whi[e0] = make_uint4(p[0], p[1], p[2], p[3]);
    *(uint4*)&Wlo[e0] = make_uint4(q[0], q[1], q[2], q[3]);
}

__global__ __launch_bounds__(256) void convb_kernel(
    const float* __restrict__ b, float* __restrict__ bp)
{
    int i = blockIdx.x * 256 + threadIdx.x;
    if (i < VTP2) bp[i] = (i < VT) ? b[i] : -1e30f;
}

// ---------------- fused gates GEMM + LSTM cell: 64x128 tile, 256 thr, 3 blocks/CU ----------------
// Wave = col quarter (32 gate-cols); acc[4][2]; permuted gate layout col 4q+gate.
__global__ __launch_bounds__(256) void gatescell_kernel(
    const ushort* __restrict__ Xhi, const ushort* __restrict__ Xlo,
    const ushort* __restrict__ Hhi, const ushort* __restrict__ Hlo,
    const ushort* __restrict__ WihH, const ushort* __restrict__ WihL,
    const ushort* __restrict__ WhhH, const ushort* __restrict__ WhhL,
    const float* __restrict__ bperm,
    float* __restrict__ Cst,
    ushort* __restrict__ OHhi, ushort* __restrict__ OHlo,
    int nk)
{
    __shared__ __align__(16) char smem[49152];   // 2 x 24 KB staging; epilogue reuses 33.8 KB
    ushort* S0 = (ushort*)smem;

    const int t = threadIdx.x;
    const int n = blockIdx.x;            // 512 blocks
    const int xcd = n & 7;
    const int rest = n >> 3;             // 0..63
    const int tile = xcd * 2 + (rest & 1);  // 0..15 (gate-col tile of 128)
    const int rb = rest >> 1;            // 0..31 (row block of 64)
    const int bj0 = tile * 128;
    const int bi0 = rb * 64;
    const int il = t & 15;
    const int g  = (t >> 4) & 3;
    const int wid = t >> 6;              // 0..3
    const int lane = t & 63;
    const int wc = wid;                  // col quarter

    int aofs[4], bofs[2];
    #pragma unroll
    for (int m = 0; m < 4; ++m) {
        int r = m * 16 + il;                                 // 0..63
        aofs[m] = r * 32 + (((g + (r >> 1)) & 3) << 3);
    }
    #pragma unroll
    for (int nn = 0; nn < 2; ++nn) {
        int r = wc * 32 + nn * 16 + il;                      // 0..127
        bofs[nn] = 4096 + r * 32 + (((g + (r >> 1)) & 3) << 3);
    }

    f32x4 acc[4][2];
    #pragma unroll
    for (int m = 0; m < 4; ++m)
        #pragma unroll
        for (int nn = 0; nn < 2; ++nn) acc[m][nn] = 0.0f;

    stage6b(S0, Xhi, Xlo, WihH, WihL, bi0, bj0, EMB, 0, wid, lane);

    for (int ks = 0; ks < nk; ++ks) {
        int cur = ks & 1;
        if (ks + 1 < nk) {
            int kn = ks + 1;
            if (kn < 4) stage6b(S0 + (cur ^ 1) * 12288, Xhi, Xlo, WihH, WihL, bi0, bj0, EMB, kn * 32, wid, lane);
            else        stage6b(S0 + (cur ^ 1) * 12288, Hhi, Hlo, WhhH, WhhL, bi0, bj0, HID, (kn - 4) * 32, wid, lane);
        }
        if (ks + 1 < nk) asm volatile("s_waitcnt vmcnt(6)" ::: "memory");
        else             asm volatile("s_waitcnt vmcnt(0)" ::: "memory");
        __builtin_amdgcn_s_barrier();
        __builtin_amdgcn_sched_barrier(0);

        ushort* Sb = S0 + cur * 12288;
        bf16x8 ah[4], al[4];
        #pragma unroll
        for (int m = 0; m < 4; ++m) {
            ah[m] = *(const bf16x8*)&Sb[aofs[m]];
            al[m] = *(const bf16x8*)&Sb[2048 + aofs[m]];
        }
        #pragma unroll
        for (int nn = 0; nn < 2; ++nn) {
            bf16x8 bh = *(const bf16x8*)&Sb[bofs[nn]];
            bf16x8 bl = *(const bf16x8*)&Sb[4096 + bofs[nn]];
            #pragma unroll
            for (int m = 0; m < 4; ++m) {
                acc[m][nn] = __builtin_amdgcn_mfma_f32_16x16x32_bf16(ah[m], bh, acc[m][nn], 0, 0, 0);
                acc[m][nn] = __builtin_amdgcn_mfma_f32_16x16x32_bf16(ah[m], bl, acc[m][nn], 0, 0, 0);
                acc[m][nn] = __builtin_amdgcn_mfma_f32_16x16x32_bf16(al[m], bh, acc[m][nn], 0, 0, 0);
            }
        }
        __builtin_amdgcn_sched_barrier(0);
        __builtin_amdgcn_s_barrier();
        __builtin_amdgcn_sched_barrier(0);
    }

    // ---- epilogue: bias -> full-tile LDS transpose [64][132] -> LSTM cell ----
    float* Tr = (float*)smem;
    float bn[2];
    #pragma unroll
    for (int nn = 0; nn < 2; ++nn) bn[nn] = bperm[bj0 + wc * 32 + nn * 16 + il];

    #pragma unroll
    for (int m = 0; m < 4; ++m)
        #pragma unroll
        for (int nn = 0; nn < 2; ++nn)
            #pragma unroll
            for (int j = 0; j < 4; ++j)
                Tr[(m * 16 + g * 4 + j) * LDW + wc * 32 + nn * 16 + il]
                    = acc[m][nn][j] + bn[nn];
    __syncthreads();

    #pragma unroll
    for (int it = 0; it < 8; ++it) {
        int row = it * 8 + (t >> 5);         // 0..63
        int c4 = t & 31;
        float4 gv = *(float4*)&Tr[row * LDW + c4 * 4];   // (i,f,g,o) for one q
        float gi = sigm(gv.x), gf = sigm(gv.y), gg = tanhf(gv.z), go = sigm(gv.w);
        size_t o = (size_t)(bi0 + row) * HID + (bj0 >> 2) + c4;
        float cnew = gf * Cst[o] + gi * gg;
        float h = go * tanhf(cnew);
        Cst[o] = cnew;
        ushort hh = f2bf(h);
        OHhi[o] = hh;
        OHlo[o] = f2bf(h - bf2f(hh));
    }
}

// ---------------- split-bf16 projection GEMM: 64x128 tile, 48 KB LDS, 3 blocks/CU (995-config) ----------------
__global__ __launch_bounds__(256) void proj_kernel(
    const ushort* __restrict__ Ahi, const ushort* __restrict__ Alo,
    const ushort* __restrict__ Whi, const ushort* __restrict__ Wlo,
    const float* __restrict__ biasp,
    float* __restrict__ outmax,
    float* __restrict__ partval, int* __restrict__ partidx,
    int mode)
{
    __shared__ __align__(16) char smem[49152];   // 2 x 24 KB staging; epilogue reuses 33.8 KB
    ushort* S0 = (ushort*)smem;

    const int t = threadIdx.x;
    const int n = blockIdx.x;            // 2048 blocks
    const int xcd = n & 7;
    const int j8 = n >> 3;               // 0..255
    const int tile = xcd * 8 + (j8 & 7); // 0..63 (col tile of 128)
    const int rb = j8 >> 3;              // 0..31 (row block of 64)
    const int bj0 = tile * 128;
    const int bi0 = rb * 64;
    const int il = t & 15;
    const int g  = (t >> 4) & 3;
    const int wid = t >> 6;              // 0..3
    const int lane = t & 63;
    const int wc = wid;                  // col quarter (32 cols each)

    // ---- T14: prefetch old outmax values into registers before compute ----
    float4 oldv[8];
    const bool rmw = (mode == 2);
    if (rmw) {
        #pragma unroll
        for (int it = 0; it < 8; ++it) {
            int row2 = it * 8 + (t >> 5);
            oldv[it] = *(const float4*)&outmax[(size_t)(bi0 + row2) * VT + bj0 + (t & 31) * 4];
        }
    }

    // fragment LDS offsets (ushort): A-hi [0,2048) A-lo [2048,4096) B-hi [4096,8192) B-lo [8192,12288)
    int aofs[4], bofs[2];
    #pragma unroll
    for (int m = 0; m < 4; ++m) {
        int r = m * 16 + il;                                 // 0..63
        aofs[m] = r * 32 + (((g + (r >> 1)) & 3) << 3);
    }
    #pragma unroll
    for (int nn = 0; nn < 2; ++nn) {
        int r = wc * 32 + nn * 16 + il;                      // 0..127
        bofs[nn] = 4096 + r * 32 + (((g + (r >> 1)) & 3) << 3);
    }

    f32x4 acc[4][2];
    #pragma unroll
    for (int m = 0; m < 4; ++m)
        #pragma unroll
        for (int nn = 0; nn < 2; ++nn) acc[m][nn] = 0.0f;

    // ---- staging source pointers (6 chunks/wave), pre-swizzled; advance += 32/K-step ----
    const ushort* gp[6];
    {
        const int rl = lane >> 2, kcp = lane & 3;
        #pragma unroll
        for (int j = 0; j < 6; ++j) {
            int c = wid * 6 + j;           // 0..23
            const ushort* srcm; int base, row;
            if (c < 4)       { srcm = Ahi; base = bi0; row = c * 16 + rl; }
            else if (c < 8)  { srcm = Alo; base = bi0; row = (c - 4) * 16 + rl; }
            else if (c < 16) { srcm = Whi; base = bj0; row = (c - 8) * 16 + rl; }
            else             { srcm = Wlo; base = bj0; row = (c - 16) * 16 + rl; }
            int kc = (kcp - (row >> 1)) & 3;   // chunk rotation pre-swizzle
            gp[j] = srcm + (size_t)(base + row) * HID + kc * 8;
        }
    }

    // prologue: stage K-tile 0
    #pragma unroll
    for (int j = 0; j < 6; ++j) {
        gload16(gp[j], S0 + (wid * 6 + j) * 512);
        gp[j] += 32;
    }

    for (int ks = 0; ks < 16; ++ks) {
        int cur = ks & 1;
        if (ks + 1 < 16) {
            ushort* Sn = S0 + (cur ^ 1) * 12288;
            #pragma unroll
            for (int j = 0; j < 6; ++j) {
                gload16(gp[j], Sn + (wid * 6 + j) * 512);
                gp[j] += 32;
            }
        }
        if (ks + 1 < 16) asm volatile("s_waitcnt vmcnt(6)" ::: "memory");
        else             asm volatile("s_waitcnt vmcnt(0)" ::: "memory");
        __builtin_amdgcn_s_barrier();
        __builtin_amdgcn_sched_barrier(0);

        ushort* Sb = S0 + cur * 12288;
        bf16x8 ah[4], al[4];
        #pragma unroll
        for (int m = 0; m < 4; ++m) {
            ah[m] = *(const bf16x8*)&Sb[aofs[m]];
            al[m] = *(const bf16x8*)&Sb[2048 + aofs[m]];
        }
        #pragma unroll
        for (int nn = 0; nn < 2; ++nn) {
            bf16x8 bh = *(const bf16x8*)&Sb[bofs[nn]];
            bf16x8 bl = *(const bf16x8*)&Sb[4096 + bofs[nn]];
            #pragma unroll
            for (int m = 0; m < 4; ++m) {
                acc[m][nn] = __builtin_amdgcn_mfma_f32_16x16x32_bf16(ah[m], bh, acc[m][nn], 0, 0, 0);
                acc[m][nn] = __builtin_amdgcn_mfma_f32_16x16x32_bf16(ah[m], bl, acc[m][nn], 0, 0, 0);
                acc[m][nn] = __builtin_amdgcn_mfma_f32_16x16x32_bf16(al[m], bh, acc[m][nn], 0, 0, 0);
            }
        }
        __builtin_amdgcn_sched_barrier(0);
        __builtin_amdgcn_s_barrier();
        __builtin_amdgcn_sched_barrier(0);
    }

    // ---- epilogue: bias -> full-tile LDS transpose [64][132] -> RMW + argmax ----
    float* Tr = (float*)smem;
    float bn[2];
    #pragma unroll
    for (int nn = 0; nn < 2; ++nn) bn[nn] = biasp[bj0 + wc * 32 + nn * 16 + il];

    #pragma unroll
    for (int m = 0; m < 4; ++m)
        #pragma unroll
        for (int nn = 0; nn < 2; ++nn)
            #pragma unroll
            for (int j = 0; j < 4; ++j)
                Tr[(m * 16 + g * 4 + j) * LDW + wc * 32 + nn * 16 + il]
                    = acc[m][nn][j] + bn[nn];
    __syncthreads();

    #pragma unroll
    for (int it = 0; it < 8; ++it) {
        int row2 = it * 8 + (t >> 5);        // 0..63
        int c4 = t & 31;
        int row = bi0 + row2;
        int col = bj0 + c4 * 4;
        float4 cur = *(float4*)&Tr[row2 * LDW + c4 * 4];

        float bv = cur.x; int bix = col;
        if (cur.y > bv) { bv = cur.y; bix = col + 1; }
        if (cur.z > bv) { bv = cur.z; bix = col + 2; }
        if (cur.w > bv) { bv = cur.w; bix = col + 3; }
        #pragma unroll
        for (int off = 1; off < 32; off <<= 1) {
            float ov = __shfl_xor(bv, off, 64);
            int   oi = __shfl_xor(bix, off, 64);
            if (ov > bv || (ov == bv && oi < bix)) { bv = ov; bix = oi; }
        }
        if ((t & 31) == 0) {
            partval[(size_t)row * NTILE2 + tile] = bv;
            partidx[(size_t)row * NTILE2 + tile] = bix;
        }

        if (col < VT) {
            float4 o = cur;
            if (rmw) {
                float4 p = oldv[it];
                o.x = fmaxf(o.x, p.x); o.y = fmaxf(o.y, p.y);
                o.z = fmaxf(o.z, p.z); o.w = fmaxf(o.w, p.w);
            }
            *(float4*)&outmax[(size_t)row * VT + col] = o;
        }
    }
}

extern "C" void kernel_launch(void* const* d_in, const int* in_sizes, int n_in,
                              void* d_out, int out_size, void* d_ws, size_t ws_size,
                              hipStream_t stream) {
    const int*   src       = (const int*)d_in[0];
    const float* src_embed = (const float*)d_in[1];
    const float* tgt_embed = (const float*)d_in[2];
    const float* enc_Wih   = (const float*)d_in[3];
    const float* enc_Whh   = (const float*)d_in[4];
    const float* enc_bih   = (const float*)d_in[5];
    const float* enc_bhh   = (const float*)d_in[6];
    const float* dec_Wih   = (const float*)d_in[7];
    const float* dec_Whh   = (const float*)d_in[8];
    const float* dec_bih   = (const float*)d_in[9];
    const float* dec_bhh   = (const float*)d_in[10];
    const float* proj_W    = (const float*)d_in[11];
    const float* proj_b    = (const float*)d_in[12];
    float* out = (float*)d_out;

    char* ws = (char*)d_ws;
    float*  C     = (float*)ws;   ws += (size_t)BB * HID * 4;        // 4 MB
    float*  PV    = (float*)ws;   ws += (size_t)BB * NTILE2 * 4;     // 512 KB
    int*    PI    = (int*)ws;     ws += (size_t)BB * NTILE2 * 4;     // 512 KB
    ushort* Xhi   = (ushort*)ws;  ws += (size_t)BB * EMB * 2;
    ushort* Xlo   = (ushort*)ws;  ws += (size_t)BB * EMB * 2;
    ushort* Hhi   = (ushort*)ws;  ws += (size_t)BB * HID * 2;
    ushort* Hlo   = (ushort*)ws;  ws += (size_t)BB * HID * 2;
    ushort* PWhi  = (ushort*)ws;  ws += (size_t)VTP2 * HID * 2;      // 8 MB
    ushort* PWlo  = (ushort*)ws;  ws += (size_t)VTP2 * HID * 2;      // 8 MB
    float*  biasp = (float*)ws;   ws += (size_t)VTP2 * 4;
    ushort* eWihH = (ushort*)ws;  ws += (size_t)G4 * EMB * 2;
    ushort* eWihL = (ushort*)ws;  ws += (size_t)G4 * EMB * 2;
    ushort* eWhhH = (ushort*)ws;  ws += (size_t)G4 * HID * 2;
    ushort* eWhhL = (ushort*)ws;  ws += (size_t)G4 * HID * 2;
    ushort* dWihH = (ushort*)ws;  ws += (size_t)G4 * EMB * 2;
    ushort* dWihL = (ushort*)ws;  ws += (size_t)G4 * EMB * 2;
    ushort* dWhhH = (ushort*)ws;  ws += (size_t)G4 * HID * 2;
    ushort* dWhhL = (ushort*)ws;  ws += (size_t)G4 * HID * 2;
    float*  BSe   = (float*)ws;   ws += (size_t)G4 * 4;
    float*  BSd   = (float*)ws;   ws += (size_t)G4 * 4;

    hipMemsetAsync(C, 0, (size_t)BB * HID * 4, stream);

    // weight conversions (gate weights row-permuted to q*4+gate)
    convw_kernel<<<VTP2 * HID / 8 / 256, 256, 0, stream>>>(proj_W, PWhi, PWlo);
    convb_kernel<<<VTP2 / 256, 256, 0, stream>>>(proj_b, biasp);
    convgate_kernel<<<G4 * EMB / 8 / 256, 256, 0, stream>>>(enc_Wih, eWihH, eWihL, 7);
    convgate_kernel<<<G4 * HID / 8 / 256, 256, 0, stream>>>(enc_Whh, eWhhH, eWhhL, 9);
    convgate_kernel<<<G4 * EMB / 8 / 256, 256, 0, stream>>>(dec_Wih, dWihH, dWihL, 7);
    convgate_kernel<<<G4 * HID / 8 / 256, 256, 0, stream>>>(dec_Whh, dWhhH, dWhhL, 9);
    convgbias_kernel<<<G4 / 256, 256, 0, stream>>>(enc_bih, enc_bhh, BSe);
    convgbias_kernel<<<G4 / 256, 256, 0, stream>>>(dec_bih, dec_bhh, BSd);

    // ---- encoder: 2 steps (step 0 skips the H segment: h == 0) ----
    for (int tstep = 0; tstep < 2; ++tstep) {
        gather2_kernel<<<BB, 64, 0, stream>>>(Xhi, Xlo, src_embed, src, 0, tstep, PV, PI);
        gatescell_kernel<<<512, 256, 0, stream>>>(Xhi, Xlo, Hhi, Hlo,
            eWihH, eWihL, eWhhH, eWhhL, BSe, C, Hhi, Hlo, tstep == 0 ? 4 : 20);
    }

    // ---- decoder: 9 greedy steps ----
    for (int s = 0; s < NSTEP; ++s) {
        gather2_kernel<<<BB, 64, 0, stream>>>(Xhi, Xlo, tgt_embed, nullptr,
            (s == 0 ? 1 : 2), 0, PV, PI);
        gatescell_kernel<<<512, 256, 0, stream>>>(Xhi, Xlo, Hhi, Hlo,
            dWihH, dWihL, dWhhH, dWhhL, BSd, C, Hhi, Hlo, 20);
        proj_kernel<<<2048, 256, 0, stream>>>(Hhi, Hlo, PWhi, PWlo, biasp,
            out, PV, PI, (s == 0 ? 1 : 2));
    }
}

// Round 15
// 994.444 us; speedup vs baseline: 1.0361x; 1.0361x over previous
//
#include <hip/hip_runtime.h>
#include <math.h>

#define BB 2048
#define EMB 128
#define HID 512
#define G4 2048    // 4*HID
#define VT 8000
#define VTP2 8192  // padded vocab
#define NSTEP 9
#define NTILE2 64  // proj col tiles of 128
#define LDW 132    // epilogue transpose leading dim (floats)

typedef short bf16x8 __attribute__((ext_vector_type(8)));
typedef float f32x4 __attribute__((ext_vector_type(4)));

__device__ __forceinline__ ushort f2bf(float x) {
    uint u = __float_as_uint(x);
    uint r = (u + 0x7fffu + ((u >> 16) & 1u)) >> 16;
    return (ushort)r;
}
__device__ __forceinline__ float bf2f(ushort h) {
    return __uint_as_float(((uint)h) << 16);
}
__device__ __forceinline__ float sigm(float x) { return 1.0f / (1.0f + expf(-x)); }

// async global->LDS, 16B per lane, LDS dest = wave-uniform base + lane*16
__device__ __forceinline__ void gload16(const ushort* g, ushort* l) {
    __builtin_amdgcn_global_load_lds(
        (const __attribute__((address_space(1))) uint*)g,
        (__attribute__((address_space(3))) uint*)l, 16, 0, 0);
}

// ---- gatescell staging: 128x32 hi/lo A,B tiles (32 KB), 8 waves, 4 loads/thread ----
__device__ __forceinline__ void stage8(
    ushort* Sb,
    const ushort* __restrict__ Ah, const ushort* __restrict__ Al,
    const ushort* __restrict__ Bh, const ushort* __restrict__ Bl,
    int biA, int biB, int K, int k0, int wid, int lane)
{
    const int rl = lane >> 2, kcp = lane & 3;
    #pragma unroll
    for (int j = 0; j < 4; ++j) {
        int c = wid * 4 + j;               // 0..31, wave-uniform
        int region = c >> 3;               // 0:Ahi 1:Alo 2:Bhi 3:Blo
        int rowblk = c & 7;
        int row = rowblk * 16 + rl;
        int kc = (kcp - (row >> 1)) & 3;
        const ushort* src = (region < 2) ? (region == 0 ? Ah : Al)
                                         : (region == 2 ? Bh : Bl);
        int base = (region < 2) ? biA : biB;
        gload16(src + (size_t)(base + row) * K + k0 + kc * 8,
                Sb + region * 4096 + rowblk * 512);
    }
}

// ---------------- fused gather: (finalize-argmax | src | BOS) -> embed -> hi/lo ----------------
__global__ __launch_bounds__(64) void gather2_kernel(
    ushort* __restrict__ Xhi, ushort* __restrict__ Xlo,
    const float* __restrict__ table,
    const int* __restrict__ src, int mode, int offset,
    const float* __restrict__ partval, const int* __restrict__ partidx)
{
    int row = blockIdx.x, t = threadIdx.x;
    int tok;
    if (mode == 0) {
        tok = src[row * 2 + offset];
    } else if (mode == 1) {
        tok = 0;
    } else {
        float v = partval[(size_t)row * NTILE2 + t];
        int  ix = partidx[(size_t)row * NTILE2 + t];
        #pragma unroll
        for (int off = 1; off < 64; off <<= 1) {
            float ov = __shfl_xor(v, off, 64);
            int   oi = __shfl_xor(ix, off, 64);
            if (ov > v || (ov == v && oi < ix)) { v = ov; ix = oi; }
        }
        tok = ix;
    }
    float2 e = *(const float2*)&table[(size_t)tok * EMB + t * 2];
    ushort2 hh, hl;
    hh.x = f2bf(e.x); hl.x = f2bf(e.x - bf2f(hh.x));
    hh.y = f2bf(e.y); hl.y = f2bf(e.y - bf2f(hh.y));
    *(ushort2*)&Xhi[row * EMB + t * 2] = hh;
    *(ushort2*)&Xlo[row * EMB + t * 2] = hl;
}

// ---------------- weight conversions ----------------
__global__ __launch_bounds__(256) void convgate_kernel(
    const float* __restrict__ W, ushort* __restrict__ Whi, ushort* __restrict__ Wlo,
    int kshift)
{
    size_t e0 = ((size_t)blockIdx.x * 256 + threadIdx.x) * 8;
    int K = 1 << kshift;
    int in_row = (int)(e0 >> kshift);
    int q = in_row & 511, gate = in_row >> 9;
    size_t o0 = (((size_t)(q * 4 + gate)) << kshift) + (e0 & (K - 1));
    float4 v0 = *(const float4*)&W[e0];
    float4 v1 = *(const float4*)&W[e0 + 4];
    float x[8] = {v0.x, v0.y, v0.z, v0.w, v1.x, v1.y, v1.z, v1.w};
    uint p[4], qq[4];
    #pragma unroll
    for (int j = 0; j < 4; ++j) {
        ushort h0 = f2bf(x[2 * j]),     l0 = f2bf(x[2 * j] - bf2f(h0));
        ushort h1 = f2bf(x[2 * j + 1]), l1 = f2bf(x[2 * j + 1] - bf2f(h1));
        p[j]  = (uint)h0 | ((uint)h1 << 16);
        qq[j] = (uint)l0 | ((uint)l1 << 16);
    }
    *(uint4*)&Whi[o0] = make_uint4(p[0], p[1], p[2], p[3]);
    *(uint4*)&Wlo[o0] = make_uint4(qq[0], qq[1], qq[2], qq[3]);
}

__global__ __launch_bounds__(256) void convgbias_kernel(
    const float* __restrict__ b0, const float* __restrict__ b1, float* __restrict__ bp)
{
    int i = blockIdx.x * 256 + threadIdx.x;   // G4 threads
    int q = i >> 2, gate = i & 3;
    bp[i] = b0[gate * 512 + q] + b1[gate * 512 + q];
}

__global__ __launch_bounds__(256) void convw_kernel(
    const float* __restrict__ W, ushort* __restrict__ Whi, ushort* __restrict__ Wlo)
{
    size_t e0 = ((size_t)blockIdx.x * 256 + threadIdx.x) * 8;  // VTP2*HID/8 threads
    int row = (int)(e0 >> 9);
    uint p[4], q[4];
    if (row < VT) {
        float4 v0 = *(const float4*)&W[e0];
        float4 v1 = *(const float4*)&W[e0 + 4];
        float x[8] = {v0.x, v0.y, v0.z, v0.w, v1.x, v1.y, v1.z, v1.w};
        #pragma unroll
        for (int j = 0; j < 4; ++j) {
            ushort h0 = f2bf(x[2 * j]),     l0 = f2bf(x[2 * j] - bf2f(h0));
            ushort h1 = f2bf(x[2 * j + 1]), l1 = f2bf(x[2 * j + 1] - bf2f(h1));
            p[j] = (uint)h0 | ((uint)h1 << 16);
            q[j] = (uint)l0 | ((uint)l1 << 16);
        }
    } else {
        #pragma unroll
        for (int j = 0; j < 4; ++j) { p[j] = 0u; q[j] = 0u; }
    }
    *(uint4*)&Whi[e0] = make_uint4(p[0], p[1], p[2], p[3]);
    *(uint4*)&Wlo[e0] = make_uint4(q[0], q[1], q[2], q[3]);
}

__global__ __launch_bounds__(256) void convb_kernel(
    const float* __restrict__ b, float* __restrict__ bp)
{
    int i = blockIdx.x * 256 + threadIdx.x;
    if (i < VTP2) bp[i] = (i < VT) ? b[i] : -1e30f;
}

// ---------------- fused gates GEMM + LSTM cell: 512 thr, counted-vmcnt (995-config) ----------------
__global__ __launch_bounds__(512) void gatescell_kernel(
    const ushort* __restrict__ Xhi, const ushort* __restrict__ Xlo,
    const ushort* __restrict__ Hhi, const ushort* __restrict__ Hlo,
    const ushort* __restrict__ WihH, const ushort* __restrict__ WihL,
    const ushort* __restrict__ WhhH, const ushort* __restrict__ WhhL,
    const float* __restrict__ bperm,
    float* __restrict__ Cst,
    ushort* __restrict__ OHhi, ushort* __restrict__ OHlo,
    int nk)
{
    __shared__ __align__(16) char smem[128 * LDW * 4];   // 67.6 KB (staging uses 64 KB)
    ushort* S0 = (ushort*)smem;

    const int t = threadIdx.x;
    const int n = blockIdx.x;            // 256 blocks
    const int tile = (n & 7) * 2 + ((n >> 3) & 1);
    const int rb = n >> 4;
    const int bj0 = tile * 128;
    const int bi0 = rb * 128;
    const int il = t & 15;
    const int g  = (t >> 4) & 3;
    const int wid = t >> 6;              // 0..7
    const int lane = t & 63;
    const int wr = wid >> 2;             // 0..1
    const int wc = wid & 3;              // 0..3

    int aofs[4], bofs[2];
    #pragma unroll
    for (int m = 0; m < 4; ++m) {
        int r = wr * 64 + m * 16 + il;
        aofs[m] = r * 32 + (((g + (r >> 1)) & 3) << 3);
    }
    #pragma unroll
    for (int nn = 0; nn < 2; ++nn) {
        int r = wc * 32 + nn * 16 + il;
        bofs[nn] = 8192 + r * 32 + (((g + (r >> 1)) & 3) << 3);
    }

    f32x4 acc[4][2];
    #pragma unroll
    for (int m = 0; m < 4; ++m)
        #pragma unroll
        for (int nn = 0; nn < 2; ++nn) acc[m][nn] = 0.0f;

    stage8(S0, Xhi, Xlo, WihH, WihL, bi0, bj0, EMB, 0, wid, lane);

    for (int ks = 0; ks < nk; ++ks) {
        int cur = ks & 1;
        if (ks + 1 < nk) {
            int kn = ks + 1;
            if (kn < 4) stage8(S0 + (cur ^ 1) * 16384, Xhi, Xlo, WihH, WihL, bi0, bj0, EMB, kn * 32, wid, lane);
            else        stage8(S0 + (cur ^ 1) * 16384, Hhi, Hlo, WhhH, WhhL, bi0, bj0, HID, (kn - 4) * 32, wid, lane);
        }
        if (ks + 1 < nk) asm volatile("s_waitcnt vmcnt(4)" ::: "memory");
        else             asm volatile("s_waitcnt vmcnt(0)" ::: "memory");
        __builtin_amdgcn_s_barrier();
        __builtin_amdgcn_sched_barrier(0);

        ushort* Sb = S0 + cur * 16384;
        bf16x8 ah[4], al[4];
        #pragma unroll
        for (int m = 0; m < 4; ++m) {
            ah[m] = *(const bf16x8*)&Sb[aofs[m]];
            al[m] = *(const bf16x8*)&Sb[4096 + aofs[m]];
        }
        #pragma unroll
        for (int nn = 0; nn < 2; ++nn) {
            bf16x8 bh = *(const bf16x8*)&Sb[bofs[nn]];
            bf16x8 bl = *(const bf16x8*)&Sb[4096 + bofs[nn]];
            #pragma unroll
            for (int m = 0; m < 4; ++m) {
                acc[m][nn] = __builtin_amdgcn_mfma_f32_16x16x32_bf16(ah[m], bh, acc[m][nn], 0, 0, 0);
                acc[m][nn] = __builtin_amdgcn_mfma_f32_16x16x32_bf16(ah[m], bl, acc[m][nn], 0, 0, 0);
                acc[m][nn] = __builtin_amdgcn_mfma_f32_16x16x32_bf16(al[m], bh, acc[m][nn], 0, 0, 0);
            }
        }
        __builtin_amdgcn_sched_barrier(0);
        __builtin_amdgcn_s_barrier();
        __builtin_amdgcn_sched_barrier(0);
    }

    // ---- epilogue: bias -> full-tile LDS transpose -> LSTM cell ----
    float* Tr = (float*)smem;   // [128][LDW]
    float bn[2];
    #pragma unroll
    for (int nn = 0; nn < 2; ++nn) bn[nn] = bperm[bj0 + wc * 32 + nn * 16 + il];

    #pragma unroll
    for (int m = 0; m < 4; ++m)
        #pragma unroll
        for (int nn = 0; nn < 2; ++nn)
            #pragma unroll
            for (int j = 0; j < 4; ++j)
                Tr[(wr * 64 + m * 16 + g * 4 + j) * LDW + wc * 32 + nn * 16 + il]
                    = acc[m][nn][j] + bn[nn];
    __syncthreads();

    #pragma unroll
    for (int it = 0; it < 8; ++it) {
        int row = it * 16 + (t >> 5);        // 0..127
        int c4 = t & 31;
        float4 gv = *(float4*)&Tr[row * LDW + c4 * 4];   // (i,f,g,o) for one q
        float gi = sigm(gv.x), gf = sigm(gv.y), gg = tanhf(gv.z), go = sigm(gv.w);
        size_t o = (size_t)(bi0 + row) * HID + (bj0 >> 2) + c4;
        float cnew = gf * Cst[o] + gi * gg;
        float h = go * tanhf(cnew);
        Cst[o] = cnew;
        ushort hh = f2bf(h);
        OHhi[o] = hh;
        OHlo[o] = f2bf(h - bf2f(hh));
    }
}

// ---------------- split-bf16 projection GEMM: 64x128 tile, 48 KB LDS, 3 blocks/CU (995-config) ----------------
__global__ __launch_bounds__(256) void proj_kernel(
    const ushort* __restrict__ Ahi, const ushort* __restrict__ Alo,
    const ushort* __restrict__ Whi, const ushort* __restrict__ Wlo,
    const float* __restrict__ biasp,
    float* __restrict__ outmax,
    float* __restrict__ partval, int* __restrict__ partidx,
    int mode)
{
    __shared__ __align__(16) char smem[49152];   // 2 x 24 KB staging; epilogue reuses 33.8 KB
    ushort* S0 = (ushort*)smem;

    const int t = threadIdx.x;
    const int n = blockIdx.x;            // 2048 blocks
    const int xcd = n & 7;
    const int j8 = n >> 3;               // 0..255
    const int tile = xcd * 8 + (j8 & 7); // 0..63 (col tile of 128)
    const int rb = j8 >> 3;              // 0..31 (row block of 64)
    const int bj0 = tile * 128;
    const int bi0 = rb * 64;
    const int il = t & 15;
    const int g  = (t >> 4) & 3;
    const int wid = t >> 6;              // 0..3
    const int lane = t & 63;
    const int wc = wid;                  // col quarter (32 cols each)

    // ---- T14: prefetch old outmax values into registers before compute ----
    float4 oldv[8];
    const bool rmw = (mode == 2);
    if (rmw) {
        #pragma unroll
        for (int it = 0; it < 8; ++it) {
            int row2 = it * 8 + (t >> 5);
            oldv[it] = *(const float4*)&outmax[(size_t)(bi0 + row2) * VT + bj0 + (t & 31) * 4];
        }
    }

    // fragment LDS offsets (ushort): A-hi [0,2048) A-lo [2048,4096) B-hi [4096,8192) B-lo [8192,12288)
    int aofs[4], bofs[2];
    #pragma unroll
    for (int m = 0; m < 4; ++m) {
        int r = m * 16 + il;                                 // 0..63
        aofs[m] = r * 32 + (((g + (r >> 1)) & 3) << 3);
    }
    #pragma unroll
    for (int nn = 0; nn < 2; ++nn) {
        int r = wc * 32 + nn * 16 + il;                      // 0..127
        bofs[nn] = 4096 + r * 32 + (((g + (r >> 1)) & 3) << 3);
    }

    f32x4 acc[4][2];
    #pragma unroll
    for (int m = 0; m < 4; ++m)
        #pragma unroll
        for (int nn = 0; nn < 2; ++nn) acc[m][nn] = 0.0f;

    // ---- staging source pointers (6 chunks/wave), pre-swizzled; advance += 32/K-step ----
    const ushort* gp[6];
    {
        const int rl = lane >> 2, kcp = lane & 3;
        #pragma unroll
        for (int j = 0; j < 6; ++j) {
            int c = wid * 6 + j;           // 0..23
            const ushort* srcm; int base, row;
            if (c < 4)       { srcm = Ahi; base = bi0; row = c * 16 + rl; }
            else if (c < 8)  { srcm = Alo; base = bi0; row = (c - 4) * 16 + rl; }
            else if (c < 16) { srcm = Whi; base = bj0; row = (c - 8) * 16 + rl; }
            else             { srcm = Wlo; base = bj0; row = (c - 16) * 16 + rl; }
            int kc = (kcp - (row >> 1)) & 3;   // chunk rotation pre-swizzle
            gp[j] = srcm + (size_t)(base + row) * HID + kc * 8;
        }
    }

    // prologue: stage K-tile 0
    #pragma unroll
    for (int j = 0; j < 6; ++j) {
        gload16(gp[j], S0 + (wid * 6 + j) * 512);
        gp[j] += 32;
    }

    for (int ks = 0; ks < 16; ++ks) {
        int cur = ks & 1;
        if (ks + 1 < 16) {
            ushort* Sn = S0 + (cur ^ 1) * 12288;
            #pragma unroll
            for (int j = 0; j < 6; ++j) {
                gload16(gp[j], Sn + (wid * 6 + j) * 512);
                gp[j] += 32;
            }
        }
        if (ks + 1 < 16) asm volatile("s_waitcnt vmcnt(6)" ::: "memory");
        else             asm volatile("s_waitcnt vmcnt(0)" ::: "memory");
        __builtin_amdgcn_s_barrier();
        __builtin_amdgcn_sched_barrier(0);

        ushort* Sb = S0 + cur * 12288;
        bf16x8 ah[4], al[4];
        #pragma unroll
        for (int m = 0; m < 4; ++m) {
            ah[m] = *(const bf16x8*)&Sb[aofs[m]];
            al[m] = *(const bf16x8*)&Sb[2048 + aofs[m]];
        }
        #pragma unroll
        for (int nn = 0; nn < 2; ++nn) {
            bf16x8 bh = *(const bf16x8*)&Sb[bofs[nn]];
            bf16x8 bl = *(const bf16x8*)&Sb[4096 + bofs[nn]];
            #pragma unroll
            for (int m = 0; m < 4; ++m) {
                acc[m][nn] = __builtin_amdgcn_mfma_f32_16x16x32_bf16(ah[m], bh, acc[m][nn], 0, 0, 0);
                acc[m][nn] = __builtin_amdgcn_mfma_f32_16x16x32_bf16(ah[m], bl, acc[m][nn], 0, 0, 0);
                acc[m][nn] = __builtin_amdgcn_mfma_f32_16x16x32_bf16(al[m], bh, acc[m][nn], 0, 0, 0);
            }
        }
        __builtin_amdgcn_sched_barrier(0);
        __builtin_amdgcn_s_barrier();
        __builtin_amdgcn_sched_barrier(0);
    }

    // ---- epilogue: bias -> full-tile LDS transpose [64][132] -> RMW + argmax ----
    float* Tr = (float*)smem;
    float bn[2];
    #pragma unroll
    for (int nn = 0; nn < 2; ++nn) bn[nn] = biasp[bj0 + wc * 32 + nn * 16 + il];

    #pragma unroll
    for (int m = 0; m < 4; ++m)
        #pragma unroll
        for (int nn = 0; nn < 2; ++nn)
            #pragma unroll
            for (int j = 0; j < 4; ++j)
                Tr[(m * 16 + g * 4 + j) * LDW + wc * 32 + nn * 16 + il]
                    = acc[m][nn][j] + bn[nn];
    __syncthreads();

    #pragma unroll
    for (int it = 0; it < 8; ++it) {
        int row2 = it * 8 + (t >> 5);        // 0..63
        int c4 = t & 31;
        int row = bi0 + row2;
        int col = bj0 + c4 * 4;
        float4 cur = *(float4*)&Tr[row2 * LDW + c4 * 4];

        float bv = cur.x; int bix = col;
        if (cur.y > bv) { bv = cur.y; bix = col + 1; }
        if (cur.z > bv) { bv = cur.z; bix = col + 2; }
        if (cur.w > bv) { bv = cur.w; bix = col + 3; }
        #pragma unroll
        for (int off = 1; off < 32; off <<= 1) {
            float ov = __shfl_xor(bv, off, 64);
            int   oi = __shfl_xor(bix, off, 64);
            if (ov > bv || (ov == bv && oi < bix)) { bv = ov; bix = oi; }
        }
        if ((t & 31) == 0) {
            partval[(size_t)row * NTILE2 + tile] = bv;
            partidx[(size_t)row * NTILE2 + tile] = bix;
        }

        if (col < VT) {
            float4 o = cur;
            if (rmw) {
                float4 p = oldv[it];
                o.x = fmaxf(o.x, p.x); o.y = fmaxf(o.y, p.y);
                o.z = fmaxf(o.z, p.z); o.w = fmaxf(o.w, p.w);
            }
            *(float4*)&outmax[(size_t)row * VT + col] = o;
        }
    }
}

extern "C" void kernel_launch(void* const* d_in, const int* in_sizes, int n_in,
                              void* d_out, int out_size, void* d_ws, size_t ws_size,
                              hipStream_t stream) {
    const int*   src       = (const int*)d_in[0];
    const float* src_embed = (const float*)d_in[1];
    const float* tgt_embed = (const float*)d_in[2];
    const float* enc_Wih   = (const float*)d_in[3];
    const float* enc_Whh   = (const float*)d_in[4];
    const float* enc_bih   = (const float*)d_in[5];
    const float* enc_bhh   = (const float*)d_in[6];
    const float* dec_Wih   = (const float*)d_in[7];
    const float* dec_Whh   = (const float*)d_in[8];
    const float* dec_bih   = (const float*)d_in[9];
    const float* dec_bhh   = (const float*)d_in[10];
    const float* proj_W    = (const float*)d_in[11];
    const float* proj_b    = (const float*)d_in[12];
    float* out = (float*)d_out;

    char* ws = (char*)d_ws;
    float*  C     = (float*)ws;   ws += (size_t)BB * HID * 4;        // 4 MB
    float*  PV    = (float*)ws;   ws += (size_t)BB * NTILE2 * 4;     // 512 KB
    int*    PI    = (int*)ws;     ws += (size_t)BB * NTILE2 * 4;     // 512 KB
    ushort* Xhi   = (ushort*)ws;  ws += (size_t)BB * EMB * 2;
    ushort* Xlo   = (ushort*)ws;  ws += (size_t)BB * EMB * 2;
    ushort* Hhi   = (ushort*)ws;  ws += (size_t)BB * HID * 2;
    ushort* Hlo   = (ushort*)ws;  ws += (size_t)BB * HID * 2;
    ushort* PWhi  = (ushort*)ws;  ws += (size_t)VTP2 * HID * 2;      // 8 MB
    ushort* PWlo  = (ushort*)ws;  ws += (size_t)VTP2 * HID * 2;      // 8 MB
    float*  biasp = (float*)ws;   ws += (size_t)VTP2 * 4;
    ushort* eWihH = (ushort*)ws;  ws += (size_t)G4 * EMB * 2;
    ushort* eWihL = (ushort*)ws;  ws += (size_t)G4 * EMB * 2;
    ushort* eWhhH = (ushort*)ws;  ws += (size_t)G4 * HID * 2;
    ushort* eWhhL = (ushort*)ws;  ws += (size_t)G4 * HID * 2;
    ushort* dWihH = (ushort*)ws;  ws += (size_t)G4 * EMB * 2;
    ushort* dWihL = (ushort*)ws;  ws += (size_t)G4 * EMB * 2;
    ushort* dWhhH = (ushort*)ws;  ws += (size_t)G4 * HID * 2;
    ushort* dWhhL = (ushort*)ws;  ws += (size_t)G4 * HID * 2;
    float*  BSe   = (float*)ws;   ws += (size_t)G4 * 4;
    float*  BSd   = (float*)ws;   ws += (size_t)G4 * 4;

    hipMemsetAsync(C, 0, (size_t)BB * HID * 4, stream);

    // weight conversions (gate weights row-permuted to q*4+gate)
    convw_kernel<<<VTP2 * HID / 8 / 256, 256, 0, stream>>>(proj_W, PWhi, PWlo);
    convb_kernel<<<VTP2 / 256, 256, 0, stream>>>(proj_b, biasp);
    convgate_kernel<<<G4 * EMB / 8 / 256, 256, 0, stream>>>(enc_Wih, eWihH, eWihL, 7);
    convgate_kernel<<<G4 * HID / 8 / 256, 256, 0, stream>>>(enc_Whh, eWhhH, eWhhL, 9);
    convgate_kernel<<<G4 * EMB / 8 / 256, 256, 0, stream>>>(dec_Wih, dWihH, dWihL, 7);
    convgate_kernel<<<G4 * HID / 8 / 256, 256, 0, stream>>>(dec_Whh, dWhhH, dWhhL, 9);
    convgbias_kernel<<<G4 / 256, 256, 0, stream>>>(enc_bih, enc_bhh, BSe);
    convgbias_kernel<<<G4 / 256, 256, 0, stream>>>(dec_bih, dec_bhh, BSd);

    // ---- encoder: 2 steps (step 0 skips the H segment: h == 0) ----
    for (int tstep = 0; tstep < 2; ++tstep) {
        gather2_kernel<<<BB, 64, 0, stream>>>(Xhi, Xlo, src_embed, src, 0, tstep, PV, PI);
        gatescell_kernel<<<256, 512, 0, stream>>>(Xhi, Xlo, Hhi, Hlo,
            eWihH, eWihL, eWhhH, eWhhL, BSe, C, Hhi, Hlo, tstep == 0 ? 4 : 20);
    }

    // ---- decoder: 9 greedy steps ----
    for (int s = 0; s < NSTEP; ++s) {
        gather2_kernel<<<BB, 64, 0, stream>>>(Xhi, Xlo, tgt_embed, nullptr,
            (s == 0 ? 1 : 2), 0, PV, PI);
        gatescell_kernel<<<256, 512, 0, stream>>>(Xhi, Xlo, Hhi, Hlo,
            dWihH, dWihL, dWhhH, dWhhL, BSd, C, Hhi, Hlo, 20);
        proj_kernel<<<2048, 256, 0, stream>>>(Hhi, Hlo, PWhi, PWlo, biasp,
            out, PV, PI, (s == 0 ? 1 : 2));
    }
}